// Round 1
// baseline (786.984 us; speedup 1.0000x reference)
//
#include <hip/hip_runtime.h>
#include <hip/hip_bf16.h>

#define B_   2
#define S_   2048
#define H_   2048
#define D_   256
#define NH_  8

typedef unsigned short u16;
typedef __bf16 bf16x8 __attribute__((ext_vector_type(8)));
typedef float f32x4 __attribute__((ext_vector_type(4)));
typedef unsigned int uint4v __attribute__((ext_vector_type(4)));
typedef unsigned int uint2v __attribute__((ext_vector_type(2)));

__device__ __forceinline__ u16 f2bf(float x) {
  union { float f; unsigned u; } v; v.f = x;
  unsigned u = v.u;
  u += 0x7FFFu + ((u >> 16) & 1u);   // round-to-nearest-even
  return (u16)(u >> 16);
}
__device__ __forceinline__ float bf2f(u16 x) {
  union { unsigned u; float f; } v; v.u = ((unsigned)x) << 16;
  return v.f;
}

// ---------------------------------------------------------------------------
// Tiled NT GEMM: C[M,N] = A[M,K] * B[N,K]^T, bf16 MFMA 16x16x32, fp32 acc.
// BM=BN=128, BK=32, 256 threads = 4 waves in 2x2, each wave 64x64 (4x4 MFMA).
// Verified layouts (m89/m91/m120): A[m=lane&15][k=quad*8+j],
// B[k=quad*8+j][n=lane&15], C/D col=lane&15 row=quad*4+reg.
// ---------------------------------------------------------------------------
#define BM 128
#define BN 128
#define BK 32
#define LDSS 40   // BK + 8 pad (bf16 elems) per LDS row

enum GemmMode { MODE_PROJ = 0, MODE_QK = 1, MODE_PV = 2, MODE_WO = 3 };

template <int MODE>
__global__ __launch_bounds__(256)
void gemm_nt(const void* __restrict__ Ap, const u16* __restrict__ Bp,
             void* __restrict__ Cp, int K, int lda, int ldb, int ldc)
{
  const int bn = blockIdx.x, bm = blockIdx.y, bz = blockIdx.z;
  if (MODE == MODE_QK && bn > bm) return;  // fully-masked causal tile

  const int m0 = bm * BM, n0 = bn * BN;

  const u16*   A16 = (const u16*)Ap;
  const float* A32 = (const float*)Ap;
  const u16*   Bb  = Bp;
  float* Cf = (float*)Cp;
  u16*   Cu = (u16*)Cp;

  if constexpr (MODE == MODE_QK) {
    A16 += (size_t)bz * S_ * D_;            // Q slab (b,h)
    Bb  += (size_t)(bz >> 3) * S_ * D_;     // K slab (b)
    Cf  += (size_t)bz * S_ * S_;            // scores slab
  } else if constexpr (MODE == MODE_PV) {
    A32 += (size_t)bz * S_ * S_;            // P slab (fp32, post-softmax)
    Bb  += (size_t)(bz >> 3) * D_ * S_;     // V^T slab (b)
    Cu  += (size_t)(bz >> 3) * S_ * (NH_ * D_) + (size_t)(bz & 7) * D_;
  }

  int Keff = K;
  if constexpr (MODE == MODE_PV) {          // P[m][k]==0 for k>m
    int lim = (bm + 1) * BM;
    Keff = lim < K ? lim : K;
  }

  __shared__ __align__(16) u16 As[BM * LDSS];
  __shared__ __align__(16) u16 Bs[BN * LDSS];

  const int tid  = threadIdx.x;
  const int lane = tid & 63;
  const int wave = tid >> 6;
  const int quad = lane >> 4;
  const int l16  = lane & 15;
  const int wm   = (wave >> 1) << 6;
  const int wn   = (wave & 1) << 6;

  const f32x4 zero4 = {0.f, 0.f, 0.f, 0.f};
  f32x4 acc[4][4];
  #pragma unroll
  for (int i = 0; i < 4; i++)
    #pragma unroll
    for (int j = 0; j < 4; j++)
      acc[i][j] = zero4;

  for (int kt = 0; kt < Keff; kt += BK) {
    // ---- stage A tile (128 x 32) into As[row][k] ----
    if constexpr (MODE == MODE_PV) {        // fp32 source, convert to bf16
      #pragma unroll
      for (int i = 0; i < 4; i++) {
        int c   = tid + i * 256;
        int row = c >> 3, kc = c & 7;
        const float4 f = *(const float4*)(A32 + (size_t)(m0 + row) * lda + kt + kc * 4);
        uint2v p;
        p.x = (unsigned)f2bf(f.x) | ((unsigned)f2bf(f.y) << 16);
        p.y = (unsigned)f2bf(f.z) | ((unsigned)f2bf(f.w) << 16);
        *(uint2v*)(&As[row * LDSS + kc * 4]) = p;
      }
    } else {                                // bf16 source, 16B copies
      #pragma unroll
      for (int i = 0; i < 2; i++) {
        int c   = tid + i * 256;
        int row = c >> 2, kc = c & 3;
        *(uint4v*)(&As[row * LDSS + kc * 8]) =
            *(const uint4v*)(A16 + (size_t)(m0 + row) * lda + kt + kc * 8);
      }
    }
    // ---- stage B tile (128 x 32) into Bs[n][k] (NT source: rows are n) ----
    #pragma unroll
    for (int i = 0; i < 2; i++) {
      int c   = tid + i * 256;
      int row = c >> 2, kc = c & 3;
      *(uint4v*)(&Bs[row * LDSS + kc * 8]) =
          *(const uint4v*)(Bb + (size_t)(n0 + row) * ldb + kt + kc * 8);
    }
    __syncthreads();

    bf16x8 af[4], bfr[4];
    #pragma unroll
    for (int i = 0; i < 4; i++)
      af[i] = *(const bf16x8*)(&As[(wm + i * 16 + l16) * LDSS + quad * 8]);
    #pragma unroll
    for (int j = 0; j < 4; j++)
      bfr[j] = *(const bf16x8*)(&Bs[(wn + j * 16 + l16) * LDSS + quad * 8]);
    #pragma unroll
    for (int i = 0; i < 4; i++)
      #pragma unroll
      for (int j = 0; j < 4; j++)
        acc[i][j] = __builtin_amdgcn_mfma_f32_16x16x32_bf16(af[i], bfr[j], acc[i][j], 0, 0, 0);
    __syncthreads();
  }

  // ---- epilogue ----
  #pragma unroll
  for (int i = 0; i < 4; i++) {
    #pragma unroll
    for (int j = 0; j < 4; j++) {
      #pragma unroll
      for (int r = 0; r < 4; r++) {
        int m = m0 + wm + i * 16 + quad * 4 + r;
        int n = n0 + wn + j * 16 + l16;
        float v = acc[i][j][r];
        if constexpr (MODE == MODE_QK) {
          v *= 0.0625f;                      // D^-0.5
          if (n > m) v += -1.0e9f;           // causal mask
          Cf[(size_t)m * ldc + n] = v;
        } else if constexpr (MODE == MODE_WO) {
          Cf[(size_t)m * ldc + n] = v;
        } else {
          Cu[(size_t)m * ldc + n] = f2bf(v);
        }
      }
    }
  }
}

// ---------------------------------------------------------------------------
// fp32 -> bf16 elementwise (4 elems/thread)
// ---------------------------------------------------------------------------
__global__ __launch_bounds__(256)
void convert_bf16_kernel(const float* __restrict__ src, u16* __restrict__ dst, int n4)
{
  int i = blockIdx.x * 256 + threadIdx.x;
  if (i >= n4) return;
  float4 f = ((const float4*)src)[i];
  uint2v p;
  p.x = (unsigned)f2bf(f.x) | ((unsigned)f2bf(f.y) << 16);
  p.y = (unsigned)f2bf(f.z) | ((unsigned)f2bf(f.w) << 16);
  ((uint2v*)dst)[i] = p;
}

// ---------------------------------------------------------------------------
// fp32 KxN -> bf16 NxK transpose-convert (32x32 tiles, 256 threads)
// ---------------------------------------------------------------------------
__global__ __launch_bounds__(256)
void transpose_convert(const float* __restrict__ src, u16* __restrict__ dst, int K, int N)
{
  __shared__ float t[32][33];
  int n0 = blockIdx.x * 32, k0 = blockIdx.y * 32;
  int c = threadIdx.x & 31, r = threadIdx.x >> 5;
  #pragma unroll
  for (int rr = 0; rr < 32; rr += 8)
    t[r + rr][c] = src[(size_t)(k0 + r + rr) * N + n0 + c];
  __syncthreads();
  #pragma unroll
  for (int rr = 0; rr < 32; rr += 8)
    dst[(size_t)(n0 + r + rr) * K + k0 + c] = f2bf(t[c][r + rr]);
}

// ---------------------------------------------------------------------------
// bf16 (B,S,D) -> (B,D,S) transpose (for V^T)
// ---------------------------------------------------------------------------
__global__ __launch_bounds__(256)
void transpose_v_kernel(const u16* __restrict__ v, u16* __restrict__ vt)
{
  __shared__ u16 t[32][34];
  int b = blockIdx.z;
  int d0 = blockIdx.x * 32, s0 = blockIdx.y * 32;
  int c = threadIdx.x & 31, r = threadIdx.x >> 5;
  #pragma unroll
  for (int rr = 0; rr < 32; rr += 8)
    t[r + rr][c] = v[(size_t)b * S_ * D_ + (size_t)(s0 + r + rr) * D_ + d0 + c];
  __syncthreads();
  #pragma unroll
  for (int rr = 0; rr < 32; rr += 8)
    vt[(size_t)b * D_ * S_ + (size_t)(d0 + r + rr) * S_ + s0 + c] = t[c][r + rr];
}

// ---------------------------------------------------------------------------
// RoPE on Q: (B,S,NH*D) bf16 -> (B,NH,S,D) bf16.  d^128 pairs halves.
// ---------------------------------------------------------------------------
__global__ __launch_bounds__(256)
void rope_q_kernel(const u16* __restrict__ qraw, const float* __restrict__ cosb,
                   const float* __restrict__ sinb, u16* __restrict__ qout)
{
  int idx = blockIdx.x;                 // bs*NH + h
  int h = idx & 7, bs = idx >> 3;
  int b = bs >> 11, s = bs & (S_ - 1);
  int d = threadIdx.x;
  size_t base = (size_t)bs * (NH_ * D_) + (size_t)h * D_;
  float qv = bf2f(qraw[base + d]);
  float qp = bf2f(qraw[base + (d ^ 128)]);
  float c  = cosb[(size_t)bs * D_ + d];
  float sn = sinb[(size_t)bs * D_ + d];
  float rot = (d < 128) ? -qp : qp;
  qout[(((size_t)b * NH_ + h) * S_ + s) * D_ + d] = f2bf(qv * c + rot * sn);
}

// RoPE on K: (B,S,D) bf16 -> (B,S,D) bf16
__global__ __launch_bounds__(256)
void rope_k_kernel(const u16* __restrict__ kraw, const float* __restrict__ cosb,
                   const float* __restrict__ sinb, u16* __restrict__ kout)
{
  int bs = blockIdx.x;
  int d = threadIdx.x;
  size_t base = (size_t)bs * D_;
  float kv = bf2f(kraw[base + d]);
  float kp = bf2f(kraw[base + (d ^ 128)]);
  float c  = cosb[(size_t)bs * D_ + d];
  float sn = sinb[(size_t)bs * D_ + d];
  float rot = (d < 128) ? -kp : kp;
  kout[base + d] = f2bf(kv * c + rot * sn);
}

// ---------------------------------------------------------------------------
// Row softmax in place on (B*NH*S, S) fp32 scores; k>q written as exact 0.
// One block (256 thr) per row; 8 elems/thread.
// ---------------------------------------------------------------------------
__global__ __launch_bounds__(256)
void softmax_rows(float* __restrict__ attn)
{
  const int r = blockIdx.x;
  const int q = r & (S_ - 1);
  float* row = attn + (size_t)r * S_;
  const int t = threadIdx.x;
  const int lane = t & 63, wave = t >> 6;

  float vals[8];
  float mx = -3.0e38f;
  #pragma unroll
  for (int i = 0; i < 8; i++) {
    int k = i * 256 + t;
    float v = (k <= q) ? row[k] : -3.0e38f;
    vals[i] = v;
    mx = fmaxf(mx, v);
  }
  #pragma unroll
  for (int o = 32; o >= 1; o >>= 1) mx = fmaxf(mx, __shfl_xor(mx, o, 64));
  __shared__ float redm[4];
  if (lane == 0) redm[wave] = mx;
  __syncthreads();
  mx = fmaxf(fmaxf(redm[0], redm[1]), fmaxf(redm[2], redm[3]));

  float sum = 0.f;
  #pragma unroll
  for (int i = 0; i < 8; i++) {
    int k = i * 256 + t;
    float e = (k <= q) ? expf(vals[i] - mx) : 0.f;
    vals[i] = e;
    sum += e;
  }
  #pragma unroll
  for (int o = 32; o >= 1; o >>= 1) sum += __shfl_xor(sum, o, 64);
  __shared__ float reds[4];
  if (lane == 0) reds[wave] = sum;
  __syncthreads();
  sum = reds[0] + reds[1] + reds[2] + reds[3];

  float inv = 1.0f / sum;
  #pragma unroll
  for (int i = 0; i < 8; i++)
    row[i * 256 + t] = vals[i] * inv;
}

// ---------------------------------------------------------------------------
extern "C" void kernel_launch(void* const* d_in, const int* in_sizes, int n_in,
                              void* d_out, int out_size, void* d_ws, size_t ws_size,
                              hipStream_t stream)
{
  const float* X    = (const float*)d_in[0];
  const float* cosb = (const float*)d_in[1];
  const float* sinb = (const float*)d_in[2];
  // d_in[3] = attention_mask (pure causal; synthesized in-kernel)
  const float* Wq   = (const float*)d_in[4];
  const float* Wk   = (const float*)d_in[5];
  const float* Wv   = (const float*)d_in[6];
  const float* Wo   = (const float*)d_in[7];

  float* outO = (float*)d_out;                               // (B,S,H)
  float* outP = outO + (size_t)B_ * S_ * H_;                 // (B,NH,S,S)

  // workspace layout (u16 elems); later stages alias dead early regions
  u16* ws   = (u16*)d_ws;
  u16* Xbf  = ws;                        //  8388608  X bf16 (B*S, H)
  u16* WqT  = Xbf  + 8388608;            //  4194304  Wq^T (2048,2048)
  u16* WkT  = WqT  + 4194304;            //   524288  Wk^T (256,2048)
  u16* WvT  = WkT  + 524288;             //   524288
  u16* WoT  = WvT  + 524288;             //  4194304  Wo^T (2048,2048)
  u16* Qraw = WoT  + 4194304;            //  8388608  X@Wq (B*S, NH*D)
  u16* Kraw = Qraw + 8388608;            //  1048576  X@Wk (B*S, D)
  u16* Vraw = Kraw + 1048576;            //  1048576  X@Wv (B*S, D)
  // aliases (source regions dead by the time these are written):
  u16* Qbf  = Xbf;                       // (B,NH,S,D) post-RoPE
  u16* Kbf  = WqT;                       // (B,S,D)   post-RoPE
  u16* VT   = WqT + 1048576;             // (B,D,S)   V transposed
  u16* AObf = Qraw;                      // (B,S,NH*D) attn out pre-Wo

  // 1. convert X to bf16
  convert_bf16_kernel<<<8192, 256, 0, stream>>>(X, Xbf, 2097152);
  // 2. transpose-convert weights to bf16 NxK
  transpose_convert<<<dim3(64, 64), 256, 0, stream>>>(Wq, WqT, 2048, 2048);
  transpose_convert<<<dim3(8, 64),  256, 0, stream>>>(Wk, WkT, 2048, 256);
  transpose_convert<<<dim3(8, 64),  256, 0, stream>>>(Wv, WvT, 2048, 256);
  transpose_convert<<<dim3(64, 64), 256, 0, stream>>>(Wo, WoT, 2048, 2048);
  // 3. QKV projections (NT GEMM, bf16 out)
  gemm_nt<MODE_PROJ><<<dim3(16, 32, 1), 256, 0, stream>>>(Xbf, WqT, Qraw, 2048, 2048, 2048, 2048);
  gemm_nt<MODE_PROJ><<<dim3(2, 32, 1),  256, 0, stream>>>(Xbf, WkT, Kraw, 2048, 2048, 2048, 256);
  gemm_nt<MODE_PROJ><<<dim3(2, 32, 1),  256, 0, stream>>>(Xbf, WvT, Vraw, 2048, 2048, 2048, 256);
  // 4. RoPE + V transpose
  rope_q_kernel<<<32768, 256, 0, stream>>>(Qraw, cosb, sinb, Qbf);
  rope_k_kernel<<<4096, 256, 0, stream>>>(Kraw, cosb, sinb, Kbf);
  transpose_v_kernel<<<dim3(8, 64, 2), 256, 0, stream>>>(Vraw, VT);
  // 5. scores = QK^T * scale + causal mask -> d_out (fp32), upper tiles skipped
  gemm_nt<MODE_QK><<<dim3(16, 16, 16), 256, 0, stream>>>(Qbf, Kbf, outP, 256, 256, 256, 2048);
  // 6. softmax in place (writes zeros above diagonal)
  softmax_rows<<<32768, 256, 0, stream>>>(outP);
  // 7. attn @ V (A fp32 from d_out, K-loop truncated at diagonal)
  gemm_nt<MODE_PV><<<dim3(2, 16, 16), 256, 0, stream>>>(outP, VT, AObf, 2048, 2048, 2048, 2048);
  // 8. @ Wo -> fp32 attn_output
  gemm_nt<MODE_WO><<<dim3(16, 32, 1), 256, 0, stream>>>(AObf, WoT, outO, 2048, 2048, 2048, 2048);
}

// Round 2
// 706.415 us; speedup vs baseline: 1.1141x; 1.1141x over previous
//
#include <hip/hip_runtime.h>
#include <hip/hip_bf16.h>

#define B_   2
#define S_   2048
#define H_   2048
#define D_   256
#define NH_  8

typedef unsigned short u16;
typedef __bf16 bf16x8 __attribute__((ext_vector_type(8)));
typedef float f32x4 __attribute__((ext_vector_type(4)));
typedef unsigned int uint4v __attribute__((ext_vector_type(4)));
typedef unsigned int uint2v __attribute__((ext_vector_type(2)));

#define AS1 __attribute__((address_space(1)))
#define AS3 __attribute__((address_space(3)))

__device__ __forceinline__ u16 f2bf(float x) {
  union { float f; unsigned u; } v; v.f = x;
  unsigned u = v.u;
  u += 0x7FFFu + ((u >> 16) & 1u);   // round-to-nearest-even
  return (u16)(u >> 16);
}
__device__ __forceinline__ float bf2f(u16 x) {
  union { unsigned u; float f; } v; v.u = ((unsigned)x) << 16;
  return v.f;
}

// async 16B global -> LDS (m97 pattern; LDS dest must be wave-uniform base + lane*16)
__device__ __forceinline__ void gld_lds16(const u16* g, u16* l) {
  __builtin_amdgcn_global_load_lds((const AS1 unsigned int*)g,
                                   (AS3 unsigned int*)l, 16, 0, 0);
}

// ---------------------------------------------------------------------------
// Tiled NT GEMM: C[M,N] = A[M,K] * B[N,K]^T, bf16 MFMA 16x16x32, fp32 acc.
// BM=BN=128, BK=32, 256 thr = 4 waves 2x2, wave does 64x64 (4x4 MFMA).
// Staging via global_load_lds dwordx4, unpadded LDS (m97: 874 TF recipe).
// Layouts (m89/m91): A[m=lane&15][k=quad*8+j], B[k=quad*8+j][n=lane&15],
// C/D col=lane&15 row=quad*4+reg.
// ---------------------------------------------------------------------------
#define BM 128
#define BN 128
#define BK 32

enum GemmMode { MODE_PROJ = 0, MODE_QK = 1, MODE_PV = 2, MODE_WO = 3 };

template <int MODE>
__global__ __launch_bounds__(256)
void gemm_nt(const u16* __restrict__ A, const u16* __restrict__ Bb,
             void* __restrict__ Cp, float* __restrict__ rows,
             int K, int lda, int ldb, int ldc)
{
  const int bn = blockIdx.x, bm = blockIdx.y, bz = blockIdx.z;
  if (MODE == MODE_QK && bn > bm) return;   // fully-masked causal tile
  const int m0 = bm * BM, n0 = bn * BN;

  const u16* Ap = A;
  const u16* Bp = Bb;
  float* Cf = (float*)Cp;
  u16*   Cu = (u16*)Cp;

  if constexpr (MODE == MODE_QK) {
    Ap   += (size_t)bz * S_ * D_;           // Q slab (b,h)
    Bp   += (size_t)(bz >> 3) * S_ * D_;    // K slab (b)
    Cu   += (size_t)bz * S_ * S_;           // E slab (bf16, unnormalized exp)
    rows += (size_t)bz * S_;
  } else if constexpr (MODE == MODE_PV) {
    Ap   += (size_t)bz * S_ * S_;           // E slab (bf16)
    Bp   += (size_t)(bz >> 3) * D_ * S_;    // V^T slab (b)
    Cu   += (size_t)(bz >> 3) * S_ * (NH_ * D_) + (size_t)(bz & 7) * D_;
    rows += (size_t)bz * S_;
  }

  int Keff = K;
  if constexpr (MODE == MODE_PV) {          // E[m][k]==0 for k>m
    int lim = (bm + 1) * BM;
    Keff = lim < K ? lim : K;
  }

  __shared__ __align__(16) u16 As[BM * BK];
  __shared__ __align__(16) u16 Bs[BN * BK];

  const int tid  = threadIdx.x;
  const int lane = tid & 63;
  const int quad = lane >> 4;
  const int l16  = lane & 15;
  const int wave = tid >> 6;
  const int wm   = (wave >> 1) << 6;
  const int wn   = (wave & 1) << 6;

  f32x4 acc[4][4] = {};

  for (int kt = 0; kt < Keff; kt += BK) {
    #pragma unroll
    for (int i = 0; i < 2; i++) {
      int c = tid + i * 256;                // chunk id; lanes consecutive in LDS
      gld_lds16(Ap + (size_t)(m0 + (c >> 2)) * lda + kt + (c & 3) * 8, &As[c * 8]);
    }
    #pragma unroll
    for (int i = 0; i < 2; i++) {
      int c = tid + i * 256;
      gld_lds16(Bp + (size_t)(n0 + (c >> 2)) * ldb + kt + (c & 3) * 8, &Bs[c * 8]);
    }
    __syncthreads();                        // compiler drains vmcnt before barrier

    bf16x8 af[4], bfr[4];
    #pragma unroll
    for (int i = 0; i < 4; i++)
      af[i] = *(const bf16x8*)(&As[(wm + i * 16 + l16) * BK + quad * 8]);
    #pragma unroll
    for (int j = 0; j < 4; j++)
      bfr[j] = *(const bf16x8*)(&Bs[(wn + j * 16 + l16) * BK + quad * 8]);
    #pragma unroll
    for (int i = 0; i < 4; i++)
      #pragma unroll
      for (int j = 0; j < 4; j++)
        acc[i][j] = __builtin_amdgcn_mfma_f32_16x16x32_bf16(af[i], bfr[j], acc[i][j], 0, 0, 0);
    __syncthreads();
  }

  // ---- epilogue ----
  const float SCL2 = 0.0625f * 1.44269504088896340736f;  // D^-0.5 * log2(e)
  #pragma unroll
  for (int i = 0; i < 4; i++) {
    #pragma unroll
    for (int r = 0; r < 4; r++) {
      const int m = m0 + wm + i * 16 + quad * 4 + r;
      if constexpr (MODE == MODE_QK) {
        float rs = 0.f;
        #pragma unroll
        for (int j = 0; j < 4; j++) {
          int n = n0 + wn + j * 16 + l16;
          float e = (n <= m) ? exp2f(acc[i][j][r] * SCL2) : 0.f;
          rs += e;
          Cu[(size_t)m * ldc + n] = f2bf(e);
        }
        #pragma unroll
        for (int o = 1; o < 16; o <<= 1) rs += __shfl_xor(rs, o, 64);
        if (l16 == 0) atomicAdd(&rows[m], rs);
      } else if constexpr (MODE == MODE_PV) {
        float inv = 1.0f / rows[m];
        #pragma unroll
        for (int j = 0; j < 4; j++) {
          int n = n0 + wn + j * 16 + l16;
          Cu[(size_t)m * ldc + n] = f2bf(acc[i][j][r] * inv);
        }
      } else if constexpr (MODE == MODE_WO) {
        #pragma unroll
        for (int j = 0; j < 4; j++) {
          int n = n0 + wn + j * 16 + l16;
          Cf[(size_t)m * ldc + n] = acc[i][j][r];
        }
      } else {
        #pragma unroll
        for (int j = 0; j < 4; j++) {
          int n = n0 + wn + j * 16 + l16;
          Cu[(size_t)m * ldc + n] = f2bf(acc[i][j][r]);
        }
      }
    }
  }
}

// ---------------------------------------------------------------------------
// fp32 -> bf16 elementwise (4 elems/thread)
// ---------------------------------------------------------------------------
__global__ __launch_bounds__(256)
void convert_bf16_kernel(const float* __restrict__ src, u16* __restrict__ dst, int n4)
{
  int i = blockIdx.x * 256 + threadIdx.x;
  if (i >= n4) return;
  float4 f = ((const float4*)src)[i];
  uint2v p;
  p.x = (unsigned)f2bf(f.x) | ((unsigned)f2bf(f.y) << 16);
  p.y = (unsigned)f2bf(f.z) | ((unsigned)f2bf(f.w) << 16);
  ((uint2v*)dst)[i] = p;
}

// ---------------------------------------------------------------------------
// fp32 KxN -> bf16 NxK transpose-convert (32x32 tiles)
// ---------------------------------------------------------------------------
__global__ __launch_bounds__(256)
void transpose_convert(const float* __restrict__ src, u16* __restrict__ dst, int K, int N)
{
  __shared__ float t[32][33];
  int n0 = blockIdx.x * 32, k0 = blockIdx.y * 32;
  int c = threadIdx.x & 31, r = threadIdx.x >> 5;
  #pragma unroll
  for (int rr = 0; rr < 32; rr += 8)
    t[r + rr][c] = src[(size_t)(k0 + r + rr) * N + n0 + c];
  __syncthreads();
  #pragma unroll
  for (int rr = 0; rr < 32; rr += 8)
    dst[(size_t)(n0 + r + rr) * K + k0 + c] = f2bf(t[c][r + rr]);
}

// ---------------------------------------------------------------------------
// V columns of QKVraw (B,S,2560)[:,2304:2560] -> VT (B,D,S) bf16
// ---------------------------------------------------------------------------
__global__ __launch_bounds__(256)
void transpose_v_kernel(const u16* __restrict__ v, u16* __restrict__ vt)
{
  __shared__ u16 t[32][34];
  int b = blockIdx.z;
  int d0 = blockIdx.x * 32, s0 = blockIdx.y * 32;
  int c = threadIdx.x & 31, r = threadIdx.x >> 5;
  #pragma unroll
  for (int rr = 0; rr < 32; rr += 8)
    t[r + rr][c] = v[(size_t)(b * S_ + s0 + r + rr) * 2560 + 2304 + d0 + c];
  __syncthreads();
  #pragma unroll
  for (int rr = 0; rr < 32; rr += 8)
    vt[(size_t)b * D_ * S_ + (size_t)(d0 + r + rr) * S_ + s0 + c] = t[c][r + rr];
}

// ---------------------------------------------------------------------------
// RoPE on Q: QKVraw (B,S,2560)[:, h*256 .. ] -> (B,NH,S,D) bf16
// ---------------------------------------------------------------------------
__global__ __launch_bounds__(256)
void rope_q_kernel(const u16* __restrict__ qraw, const float* __restrict__ cosb,
                   const float* __restrict__ sinb, u16* __restrict__ qout)
{
  int idx = blockIdx.x;                 // bs*NH + h
  int h = idx & 7, bs = idx >> 3;
  int b = bs >> 11, s = bs & (S_ - 1);
  int d = threadIdx.x;
  size_t base = (size_t)bs * 2560 + (size_t)h * D_;
  float qv = bf2f(qraw[base + d]);
  float qp = bf2f(qraw[base + (d ^ 128)]);
  float c  = cosb[(size_t)bs * D_ + d];
  float sn = sinb[(size_t)bs * D_ + d];
  float rot = (d < 128) ? -qp : qp;
  qout[(((size_t)b * NH_ + h) * S_ + s) * D_ + d] = f2bf(qv * c + rot * sn);
}

// RoPE on K: QKVraw[:, 2048..2304] -> (B,S,D) bf16
__global__ __launch_bounds__(256)
void rope_k_kernel(const u16* __restrict__ kraw, const float* __restrict__ cosb,
                   const float* __restrict__ sinb, u16* __restrict__ kout)
{
  int bs = blockIdx.x;
  int d = threadIdx.x;
  size_t base = (size_t)bs * 2560 + 2048;
  float kv = bf2f(kraw[base + d]);
  float kp = bf2f(kraw[base + (d ^ 128)]);
  float c  = cosb[(size_t)bs * D_ + d];
  float sn = sinb[(size_t)bs * D_ + d];
  float rot = (d < 128) ? -kp : kp;
  kout[(size_t)bs * D_ + d] = f2bf(kv * c + rot * sn);
}

// ---------------------------------------------------------------------------
// P[r][k] = E[r][k] * inv(rowsum[r]) as fp32 (zeros above diagonal).
// One block per row, 8 cols/thread, fully vectorized.
// ---------------------------------------------------------------------------
__global__ __launch_bounds__(256)
void normalize_p(const u16* __restrict__ E, const float* __restrict__ rows,
                 float* __restrict__ P)
{
  const int r = blockIdx.x;
  const int q = r & (S_ - 1);
  const u16* e = E + (size_t)r * S_;
  float* p = P + (size_t)r * S_;
  const float inv = 1.0f / rows[r];
  const int k0 = threadIdx.x * 8;

  float4 lo = {0.f, 0.f, 0.f, 0.f}, hi = {0.f, 0.f, 0.f, 0.f};
  if (k0 <= q) {                          // chunks fully above diagonal: pure zeros
    uint4v u = *(const uint4v*)(e + k0);
    float v[8];
    v[0] = bf2f(u.x & 0xffff); v[1] = bf2f(u.x >> 16);
    v[2] = bf2f(u.y & 0xffff); v[3] = bf2f(u.y >> 16);
    v[4] = bf2f(u.z & 0xffff); v[5] = bf2f(u.z >> 16);
    v[6] = bf2f(u.w & 0xffff); v[7] = bf2f(u.w >> 16);
    lo.x = (k0 + 0 <= q) ? v[0] * inv : 0.f;
    lo.y = (k0 + 1 <= q) ? v[1] * inv : 0.f;
    lo.z = (k0 + 2 <= q) ? v[2] * inv : 0.f;
    lo.w = (k0 + 3 <= q) ? v[3] * inv : 0.f;
    hi.x = (k0 + 4 <= q) ? v[4] * inv : 0.f;
    hi.y = (k0 + 5 <= q) ? v[5] * inv : 0.f;
    hi.z = (k0 + 6 <= q) ? v[6] * inv : 0.f;
    hi.w = (k0 + 7 <= q) ? v[7] * inv : 0.f;
  }
  *(float4*)(p + k0)     = lo;
  *(float4*)(p + k0 + 4) = hi;
}

// ---------------------------------------------------------------------------
extern "C" void kernel_launch(void* const* d_in, const int* in_sizes, int n_in,
                              void* d_out, int out_size, void* d_ws, size_t ws_size,
                              hipStream_t stream)
{
  const float* X    = (const float*)d_in[0];
  const float* cosb = (const float*)d_in[1];
  const float* sinb = (const float*)d_in[2];
  // d_in[3] = attention_mask (pure causal; synthesized in-kernel)
  const float* Wq   = (const float*)d_in[4];
  const float* Wk   = (const float*)d_in[5];
  const float* Wv   = (const float*)d_in[6];
  const float* Wo   = (const float*)d_in[7];

  float* outO = (float*)d_out;                               // (B,S,H) fp32
  float* outP = outO + (size_t)B_ * S_ * H_;                 // (B,NH,S,S) fp32

  // workspace layout (u16 elems), no aliasing (~229 MB total)
  u16* ws     = (u16*)d_ws;
  u16* Xbf    = ws;                          //  8,388,608  X bf16 (B*S, H)
  u16* WT     = Xbf    + 8388608;            //  5,242,880  packed [Wq|Wk|Wv]^T (2560,2048)
  u16* WoT    = WT     + 5242880;            //  4,194,304  Wo^T (2048,2048)
  u16* QKVraw = WoT    + 4194304;            // 10,485,760  X@W (B*S, 2560)
  u16* Qbf    = QKVraw + 10485760;           //  8,388,608  (B,NH,S,D) post-RoPE
  u16* Kbf    = Qbf    + 8388608;            //  1,048,576  (B,S,D)   post-RoPE
  u16* VT     = Kbf    + 1048576;            //  1,048,576  (B,D,S)
  u16* AObf   = VT     + 1048576;            //  8,388,608  (B,S,NH*D)
  u16* Ebf    = AObf   + 8388608;            // 67,108,864  unnormalized exp (B,NH,S,S)
  float* Rows = (float*)(Ebf + 67108864);    //     32,768  fp32 row sums

  // 1. X -> bf16
  convert_bf16_kernel<<<8192, 256, 0, stream>>>(X, Xbf, 2097152);
  // 2. weights -> bf16, transposed; Q|K|V packed into one (2560,2048)
  transpose_convert<<<dim3(64, 64), 256, 0, stream>>>(Wq, WT, 2048, 2048);
  transpose_convert<<<dim3(8, 64),  256, 0, stream>>>(Wk, WT + 2048 * 2048, 2048, 256);
  transpose_convert<<<dim3(8, 64),  256, 0, stream>>>(Wv, WT + 2304 * 2048, 2048, 256);
  transpose_convert<<<dim3(64, 64), 256, 0, stream>>>(Wo, WoT, 2048, 2048);
  // 3. fused QKV projection (one GEMM, N=2560)
  gemm_nt<MODE_PROJ><<<dim3(20, 32, 1), 256, 0, stream>>>(
      Xbf, WT, QKVraw, nullptr, 2048, 2048, 2048, 2560);
  // 4. RoPE + V transpose
  rope_q_kernel<<<32768, 256, 0, stream>>>(QKVraw, cosb, sinb, Qbf);
  rope_k_kernel<<<4096, 256, 0, stream>>>(QKVraw, cosb, sinb, Kbf);
  transpose_v_kernel<<<dim3(8, 64, 2), 256, 0, stream>>>(QKVraw, VT);
  // 5. E = exp(QK^T * scale) bf16 (lower-tri; zeros on diag tile), rowsums via atomics
  hipMemsetAsync(Rows, 0, 32768 * sizeof(float), stream);
  gemm_nt<MODE_QK><<<dim3(16, 16, 16), 256, 0, stream>>>(
      Qbf, Kbf, Ebf, Rows, 256, 256, 256, 2048);
  // 6. P (fp32, d_out) = E * inv(rowsum), zeros above diagonal
  normalize_p<<<32768, 256, 0, stream>>>(Ebf, Rows, outP);
  // 7. attn_out = (E @ V) * inv(rowsum), K-loop truncated at diagonal
  gemm_nt<MODE_PV><<<dim3(2, 16, 16), 256, 0, stream>>>(
      Ebf, VT, AObf, Rows, 2048, 2048, 2048, 2048);
  // 8. @ Wo -> fp32 attn_output
  gemm_nt<MODE_WO><<<dim3(16, 32, 1), 256, 0, stream>>>(
      AObf, WoT, outO, nullptr, 2048, 2048, 2048, 2048);
}